// Round 3
// baseline (100.777 us; speedup 1.0000x reference)
//
#include <hip/hip_runtime.h>

// Tropical (max-plus) matmul: out[n,m] = max_k(|x[n,k]| + |w[m,k]|)
// N=1024, K=256, M=1024, fp32.
//
// Round 3: LDS-traffic + occupancy fixed simultaneously.
//  - 4x4 register tile per thread -> 2 B LDS per (output,k): half of R2.
//  - 64x64 output tile, 256 threads; split-K=4 -> 1024 blocks = 4 blocks/CU
//    = 4 waves/SIMD (R1's 4x4 design had only 1 wave/SIMD).
//  - Each block handles one K-slice of 64: single staging phase, ONE barrier,
//    fully unrolled 32 k-pair inner loop (v_pk_add_f32 + v_max3_f32).
//  - Partials combined with atomicMax on int bit-pattern: all results are
//    >= 0 so IEEE bits are order-isomorphic; both 0x00 (memset) and
//    0xAAAAAAAA (poison, negative as int) lose to any non-negative float.

typedef float v2f __attribute__((ext_vector_type(2)));
typedef float v4f __attribute__((ext_vector_type(4)));

constexpr int PITCH = 66;  // v2f units per k-pair row: 64 + 2 pad = 528 B (16B-aligned)

__global__ void __launch_bounds__(256, 4)
tropical_kernel(const float* __restrict__ xg, const float* __restrict__ wg,
                float* __restrict__ outg)
{
    constexpr int K = 256;
    constexpr int M = 1024;

    __shared__ __align__(16) v2f xs[32 * PITCH];
    __shared__ __align__(16) v2f ws[32 * PITCH];

    const int bid  = blockIdx.x;
    const int ks   = bid >> 8;        // k-slice 0..3 (tile-major: 4 writers of a
    const int tile = bid & 255;       // tile are 256 blocks apart -> staggered atomics)
    const int bn = (tile >> 4) * 64;
    const int bm = (tile & 15) * 64;
    const int k0 = ks * 64;

    const int tid = threadIdx.x;
    const int tx = tid & 15;          // m-side, 4 cols per thread
    const int ty = tid >> 4;          // n-side, 4 rows per thread

    // ---- Stage this block's 64x64 x-slice and w-slice into LDS (k-pair-major).
    // Thread: row = tid>>2 (0..63), k-cols [kc, kc+16).
    const int row = tid >> 2;
    const int kc  = (tid & 3) * 16;
    const float* xp = xg + (bn + row) * K + k0 + kc;
    const float* wp = wg + (bm + row) * K + k0 + kc;
    v4f xl[4], wl[4];
#pragma unroll
    for (int i = 0; i < 4; ++i) {
        xl[i] = *(const v4f*)(xp + 4 * i);
        wl[i] = *(const v4f*)(wp + 4 * i);
    }
    const int kp0 = kc >> 1;
#pragma unroll
    for (int i = 0; i < 4; ++i) {
        xs[(kp0 + 2 * i    ) * PITCH + row] = (v2f){fabsf(xl[i].x), fabsf(xl[i].y)};
        xs[(kp0 + 2 * i + 1) * PITCH + row] = (v2f){fabsf(xl[i].z), fabsf(xl[i].w)};
        ws[(kp0 + 2 * i    ) * PITCH + row] = (v2f){fabsf(wl[i].x), fabsf(wl[i].y)};
        ws[(kp0 + 2 * i + 1) * PITCH + row] = (v2f){fabsf(wl[i].z), fabsf(wl[i].w)};
    }
    __syncthreads();

    // ---- 32 k-pairs, 4x4 outputs: per kk, 4 ds_read_b128 + 16 pk_add + 16 max3.
    float acc[4][4] = {};
#pragma unroll
    for (int kk = 0; kk < 32; ++kk) {
        const v2f* xr = &xs[kk * PITCH + 4 * ty];
        const v2f* wr = &ws[kk * PITCH + 4 * tx];
        v4f xa = *(const v4f*)xr, xb = *(const v4f*)(xr + 2);
        v4f wa = *(const v4f*)wr, wb = *(const v4f*)(wr + 2);
        v2f xpair[4] = {{xa.x, xa.y}, {xa.z, xa.w}, {xb.x, xb.y}, {xb.z, xb.w}};
        v2f wpair[4] = {{wa.x, wa.y}, {wa.z, wa.w}, {wb.x, wb.y}, {wb.z, wb.w}};
#pragma unroll
        for (int i = 0; i < 4; ++i)
#pragma unroll
            for (int j = 0; j < 4; ++j) {
                v2f s = xpair[i] + wpair[j];                       // v_pk_add_f32
                acc[i][j] = fmaxf(acc[i][j], fmaxf(s.x, s.y));    // v_max3_f32
            }
    }

    // ---- Combine k-slices: integer atomicMax (values >= 0 -> bits monotone).
    int* op = (int*)outg;
#pragma unroll
    for (int i = 0; i < 4; ++i) {
        const int base = (bn + 4 * ty + i) * M + bm + 4 * tx;
#pragma unroll
        for (int j = 0; j < 4; ++j)
            atomicMax(&op[base + j], __float_as_int(acc[i][j]));
    }
}

extern "C" void kernel_launch(void* const* d_in, const int* in_sizes, int n_in,
                              void* d_out, int out_size, void* d_ws, size_t ws_size,
                              hipStream_t stream)
{
    const float* x = (const float*)d_in[0];   // [1024, 256]
    const float* w = (const float*)d_in[1];   // [1024, 256]
    float* out = (float*)d_out;               // [1024, 1024]

    dim3 grid(1024);   // 256 tiles (16x16 of 64x64) x 4 k-slices
    dim3 block(256);
    tropical_kernel<<<grid, block, 0, stream>>>(x, w, out);
}

// Round 4
// 78.112 us; speedup vs baseline: 1.2902x; 1.2902x over previous
//
#include <hip/hip_runtime.h>

// Tropical (max-plus) matmul: out[n,m] = max_k(|x[n,k]| + |w[m,k]|)
// N=1024, K=256, M=1024, fp32.
//
// Round 4: kill the atomic epilogue (R3: 67 MB WRITE_SIZE) AND halve+ the
// LDS inner-loop traffic by making the x-operand wave-uniform:
//  - lane <-> m: each wave covers 64 m (lane) x 4 n (acc regs).
//  - w[m][k] chunk lives in per-lane VGPRs, filled once per chunk via an
//    LDS transpose (coalesced global -> LDS -> per-lane rows).
//  - x[n][k] is wave-uniform (n derived from readfirstlane(tid>>6)) ->
//    scalar s_load; inner combine is v_pk_add_f32 (VGPR pair + SGPR pair)
//    + v_max3_f32: 1 inst per (out,k), NO LDS reads in the k-inner loop.
//  - stores: lane = m -> fully coalesced b32 rows, no combine step.
//  - grid 1024 blocks (64 n-tiles x 16 m-tiles) x 256 thr = 4 blocks/CU
//    = 4 waves/SIMD; LDS 17.4 KB/block.

typedef float v2f __attribute__((ext_vector_type(2)));
typedef float v4f __attribute__((ext_vector_type(4)));

constexpr int K   = 256;
constexpr int M   = 1024;
constexpr int KC  = 64;          // k per chunk
constexpr int NCH = K / KC;      // 4 chunks
constexpr int WP  = 68;          // LDS row pitch in floats (64 + 4 pad, 16B-aligned)

__global__ void __launch_bounds__(256, 4)
tropical_kernel(const float* __restrict__ xg, const float* __restrict__ wg,
                float* __restrict__ outg)
{
    __shared__ __align__(16) float wlds[64 * WP];   // 17,408 B

    const int tid  = threadIdx.x;
    const int lane = tid & 63;
    const int wv   = __builtin_amdgcn_readfirstlane(tid >> 6);  // wave id 0..3

    const int bn = (int)(blockIdx.x >> 4) * 16;   // 16 n-rows per block
    const int bm = (int)(blockIdx.x & 15) * 64;   // 64 m-cols per block

    // Staging: thread loads w row (bm + wrow), 16 consecutive k at wcol.
    const int wrow = tid >> 2;
    const int wcol = (tid & 3) * 16;
    const float* wbase = wg + (bm + wrow) * K + wcol;

    // Prefetch chunk 0.
    v4f pref[4];
#pragma unroll
    for (int i = 0; i < 4; ++i) pref[i] = *(const v4f*)(wbase + 4 * i);

    float acc[4] = {0.f, 0.f, 0.f, 0.f};   // sums >= 0: 0 is a safe identity

    const float* xrow0 = xg + (bn + 4 * wv) * K;  // wave-uniform base

    for (int c = 0; c < NCH; ++c) {
        __syncthreads();   // previous chunk's wreg transpose-reads done
#pragma unroll
        for (int i = 0; i < 4; ++i) {
            v4f t = pref[i];
            *(v4f*)&wlds[wrow * WP + wcol + 4 * i] =
                (v4f){fabsf(t.x), fabsf(t.y), fabsf(t.z), fabsf(t.w)};
        }
        if (c + 1 < NCH) {
#pragma unroll
            for (int i = 0; i < 4; ++i)
                pref[i] = *(const v4f*)(wbase + (c + 1) * KC + 4 * i);
        }
        __syncthreads();

        // Transpose-read this lane's |w| row chunk into registers
        // (16 ds_read_b128; pitch 68 floats -> 8 words/bank = conflict floor).
        v2f wreg[KC / 2];
#pragma unroll
        for (int q = 0; q < KC / 4; ++q) {
            v4f t = *(const v4f*)&wlds[lane * WP + 4 * q];
            wreg[2 * q]     = (v2f){t.x, t.y};
            wreg[2 * q + 1] = (v2f){t.z, t.w};
        }

        // Compute: 4 n-rows; x values are wave-uniform -> scalar loads.
#pragma unroll
        for (int jn = 0; jn < 4; ++jn) {
            const float* xr = xrow0 + jn * K + c * KC;
#pragma unroll
            for (int kp = 0; kp < KC / 2; ++kp) {
                v2f xu = (v2f){fabsf(xr[2 * kp]), fabsf(xr[2 * kp + 1])};
                v2f s  = wreg[kp] + xu;                      // v_pk_add_f32
                acc[jn] = fmaxf(acc[jn], fmaxf(s.x, s.y));   // v_max3_f32
            }
        }
    }

    // Store: lane = m offset -> 64 consecutive floats per row, coalesced.
#pragma unroll
    for (int jn = 0; jn < 4; ++jn)
        outg[(bn + 4 * wv + jn) * M + bm + lane] = acc[jn];
}

extern "C" void kernel_launch(void* const* d_in, const int* in_sizes, int n_in,
                              void* d_out, int out_size, void* d_ws, size_t ws_size,
                              hipStream_t stream)
{
    const float* x = (const float*)d_in[0];   // [1024, 256]
    const float* w = (const float*)d_in[1];   // [1024, 256]
    float* out = (float*)d_out;               // [1024, 1024]

    dim3 grid(1024);   // 64 n-tiles x 16 m-tiles
    dim3 block(256);
    tropical_kernel<<<grid, block, 0, stream>>>(x, w, out);
}